// Round 1
// baseline (373.707 us; speedup 1.0000x reference)
//
#include <hip/hip_runtime.h>

// Problem constants
#define N_Q 2048
#define M_K 1024
#define DIM 1024
#define EDIM 64
#define GRP 16

typedef __attribute__((ext_vector_type(8))) short short8;   // 8 bf16 (4 VGPRs)
typedef __attribute__((ext_vector_type(4))) float f32x4;    // MFMA acc

__device__ __forceinline__ unsigned short bf16r(float f) {
  unsigned int u = __float_as_uint(f);
  u = (u + 0x7FFFu + ((u >> 16) & 1u)) >> 16;
  return (unsigned short)u;
}
__device__ __forceinline__ float bf2f(unsigned short h) {
  return __uint_as_float(((unsigned int)h) << 16);
}

// ---------------- fp32 -> bf16 convert ----------------
__global__ __launch_bounds__(256)
void cvt_kernel(const float* __restrict__ src, unsigned short* __restrict__ dst, int n) {
  int stride = gridDim.x * blockDim.x * 4;
  for (int i = (blockIdx.x * blockDim.x + threadIdx.x) * 4; i < n; i += stride) {
    float4 v = *(const float4*)(src + i);
    ushort4 o;
    o.x = bf16r(v.x); o.y = bf16r(v.y); o.z = bf16r(v.z); o.w = bf16r(v.w);
    *(ushort4*)(dst + i) = o;
  }
}

// ---------------- generic NT GEMM (C = A @ B^T), bf16 in, MFMA 16x16x32 ----
// A: [M][lda] bf16 rows (K-contiguous), B: [N][ldb] bf16 rows (K-contiguous).
// Wave computes a 64x64 tile via 4x4 fragments, loaded directly from global
// (operands are small and L2-resident; no LDS staging in round 1).
// MODE 0: C=RS bf16 relu(v+bias[col]); also writes fp32 copy of rows<2048 to aux
// MODE 1: v+=bias[col]; split col->(g,j); store bf16 at C[g*M*64 + row*64 + j]
// MODE 2: split col->(g,j); store bf16 TRANSPOSED at C[g*65536 + j*1024 + row]
// MODE 3: v*=log2(e)/8; store bf16 at C[z*2097152 + row*1024 + col]
// MODE 4: out fp32: C[row*1024 + z*64+col] = v + wvb[z*64+col] + aux[row*1024+z*64+col]
template<int WR, int WC, int MODE>
__global__ __launch_bounds__(WR*WC*64)
void gemm_nt(const unsigned short* __restrict__ A,
             const unsigned short* __restrict__ B,
             void* __restrict__ C,
             const float* __restrict__ bias,
             float* __restrict__ aux,
             const float* __restrict__ wvb,
             int M, int K, int lda, int ldb,
             long aBatch, long bBatch)
{
  const int z = blockIdx.z;
  const unsigned short* Ab = A + (long)z * aBatch;
  const unsigned short* Bb = B + (long)z * bBatch;
  const int t = threadIdx.x;
  const int lane = t & 63;
  const int w = t >> 6;
  const int wr = w / WC, wc = w % WC;
  const int row0 = blockIdx.x * (WR * 64) + wr * 64;
  const int col0 = blockIdx.y * (WC * 64) + wc * 64;
  const int r  = lane & 15;
  const int kk = (lane >> 4) << 3;

  f32x4 acc[4][4] = {};

  for (int k0 = 0; k0 < K; k0 += 32) {
    short8 a[4], b[4];
#pragma unroll
    for (int i = 0; i < 4; ++i)
      a[i] = *(const short8*)(Ab + (long)(row0 + i * 16 + r) * lda + k0 + kk);
#pragma unroll
    for (int j = 0; j < 4; ++j)
      b[j] = *(const short8*)(Bb + (long)(col0 + j * 16 + r) * ldb + k0 + kk);
#pragma unroll
    for (int i = 0; i < 4; ++i)
#pragma unroll
      for (int j = 0; j < 4; ++j)
        acc[i][j] = __builtin_amdgcn_mfma_f32_16x16x32_bf16(a[i], b[j], acc[i][j], 0, 0, 0);
  }

  const int rbase = (lane >> 4) << 2;
  const int cidx  = lane & 15;
#pragma unroll
  for (int i = 0; i < 4; ++i) {
#pragma unroll
    for (int j = 0; j < 4; ++j) {
#pragma unroll
      for (int ri = 0; ri < 4; ++ri) {
        int rr = row0 + i * 16 + rbase + ri;
        int cc = col0 + j * 16 + cidx;
        float v = acc[i][j][ri];
        if (MODE == 0) {
          v += bias[cc];
          v = fmaxf(v, 0.f);
          ((unsigned short*)C)[(long)rr * DIM + cc] = bf16r(v);
          if (rr < N_Q) aux[(long)rr * DIM + cc] = v;
        } else if (MODE == 1) {
          v += bias[cc];
          int g = cc >> 6, jj = cc & 63;
          ((unsigned short*)C)[(long)g * M * 64 + (long)rr * 64 + jj] = bf16r(v);
        } else if (MODE == 2) {
          int g = cc >> 6, jj = cc & 63;
          ((unsigned short*)C)[(long)g * 65536 + (long)jj * 1024 + rr] = bf16r(v);
        } else if (MODE == 3) {
          v *= 0.18033688011112042f;  // log2(e)/8
          ((unsigned short*)C)[(long)z * 2097152 + (long)rr * 1024 + cc] = bf16r(v);
        } else if (MODE == 4) {
          int oc = z * 64 + cc;
          ((float*)C)[(long)rr * DIM + oc] = v + wvb[oc] + aux[(long)rr * DIM + oc];
        }
      }
    }
  }
}

// ---------------- fused position-bias conv + softmax ----------------
// One block per n (2048 blocks, 256 threads). Thread t owns m = 4t..4t+3 for
// all 16 groups (64 fp32 accumulators). Streams pe[e][n][m] once (512 MB
// total). Base-2 softmax: w = log2(relu(conv)+1e-6) + scores (scores already
// scaled by log2(e)/8 in the scores GEMM). P written bf16 in-place over Sc.
__global__ __launch_bounds__(256)
void pe_softmax(const float* __restrict__ pe, const float* __restrict__ wgw,
                const float* __restrict__ wgb, unsigned short* __restrict__ Sc)
{
  const int n = blockIdx.x;
  const int t = threadIdx.x;
  const int lane = t & 63;
  const int wid = t >> 6;
  __shared__ __align__(16) float wgT[64][16];
  __shared__ float redM[4][16];
  __shared__ float redS[4][16];
  for (int i = t; i < 1024; i += 256) wgT[i & 63][i >> 6] = wgw[i];
  __syncthreads();

  float acc[64];
#pragma unroll
  for (int g = 0; g < 16; ++g) {
    float bb = wgb[g];
#pragma unroll
    for (int mm = 0; mm < 4; ++mm) acc[g * 4 + mm] = bb;
  }

  const float* pebase = pe + (long)n * 1024 + t * 4;
#pragma unroll 2
  for (int e = 0; e < 64; ++e) {
    float4 p = *(const float4*)(pebase + (long)e * 2097152);
    const f32x4* wrow = (const f32x4*)(&wgT[e][0]);
    f32x4 w0 = wrow[0], w1 = wrow[1], w2 = wrow[2], w3 = wrow[3];
    float wg16[16] = {w0[0], w0[1], w0[2], w0[3], w1[0], w1[1], w1[2], w1[3],
                      w2[0], w2[1], w2[2], w2[3], w3[0], w3[1], w3[2], w3[3]};
#pragma unroll
    for (int g = 0; g < 16; ++g) {
      acc[g * 4 + 0] = fmaf(wg16[g], p.x, acc[g * 4 + 0]);
      acc[g * 4 + 1] = fmaf(wg16[g], p.y, acc[g * 4 + 1]);
      acc[g * 4 + 2] = fmaf(wg16[g], p.z, acc[g * 4 + 2]);
      acc[g * 4 + 3] = fmaf(wg16[g], p.w, acc[g * 4 + 3]);
    }
  }

  // log2(relu + 1e-6) + scores
#pragma unroll
  for (int g = 0; g < 16; ++g) {
    ushort4 s4 = *(const ushort4*)(Sc + (long)g * 2097152 + (long)n * 1024 + t * 4);
    float s0 = bf2f(s4.x), s1 = bf2f(s4.y), s2 = bf2f(s4.z), s3 = bf2f(s4.w);
    acc[g * 4 + 0] = __builtin_amdgcn_logf(fmaxf(acc[g * 4 + 0], 0.f) + 1e-6f) + s0;
    acc[g * 4 + 1] = __builtin_amdgcn_logf(fmaxf(acc[g * 4 + 1], 0.f) + 1e-6f) + s1;
    acc[g * 4 + 2] = __builtin_amdgcn_logf(fmaxf(acc[g * 4 + 2], 0.f) + 1e-6f) + s2;
    acc[g * 4 + 3] = __builtin_amdgcn_logf(fmaxf(acc[g * 4 + 3], 0.f) + 1e-6f) + s3;
  }

  // per-(n,g) max
  float gmax[16];
#pragma unroll
  for (int g = 0; g < 16; ++g) {
    float m = fmaxf(fmaxf(acc[g * 4 + 0], acc[g * 4 + 1]),
                    fmaxf(acc[g * 4 + 2], acc[g * 4 + 3]));
#pragma unroll
    for (int off = 32; off >= 1; off >>= 1) m = fmaxf(m, __shfl_xor(m, off));
    if (lane == 0) redM[wid][g] = m;
  }
  __syncthreads();
#pragma unroll
  for (int g = 0; g < 16; ++g)
    gmax[g] = fmaxf(fmaxf(redM[0][g], redM[1][g]), fmaxf(redM[2][g], redM[3][g]));

  // exp2 sum
#pragma unroll
  for (int g = 0; g < 16; ++g) {
    float s = __builtin_amdgcn_exp2f(acc[g * 4 + 0] - gmax[g])
            + __builtin_amdgcn_exp2f(acc[g * 4 + 1] - gmax[g])
            + __builtin_amdgcn_exp2f(acc[g * 4 + 2] - gmax[g])
            + __builtin_amdgcn_exp2f(acc[g * 4 + 3] - gmax[g]);
#pragma unroll
    for (int off = 32; off >= 1; off >>= 1) s += __shfl_xor(s, off);
    if (lane == 0) redS[wid][g] = s;
  }
  __syncthreads();

  // normalize + write P bf16 in-place
#pragma unroll
  for (int g = 0; g < 16; ++g) {
    float sum = redS[0][g] + redS[1][g] + redS[2][g] + redS[3][g];
    float rs = __builtin_amdgcn_rcpf(sum);
    ushort4 o;
    o.x = bf16r(__builtin_amdgcn_exp2f(acc[g * 4 + 0] - gmax[g]) * rs);
    o.y = bf16r(__builtin_amdgcn_exp2f(acc[g * 4 + 1] - gmax[g]) * rs);
    o.z = bf16r(__builtin_amdgcn_exp2f(acc[g * 4 + 2] - gmax[g]) * rs);
    o.w = bf16r(__builtin_amdgcn_exp2f(acc[g * 4 + 3] - gmax[g]) * rs);
    *(ushort4*)(Sc + (long)g * 2097152 + (long)n * 1024 + t * 4) = o;
  }
}

extern "C" void kernel_launch(void* const* d_in, const int* in_sizes, int n_in,
                              void* d_out, int out_size, void* d_ws, size_t ws_size,
                              hipStream_t stream)
{
  const float* ref_feat = (const float*)d_in[0];
  const float* sup_feat = (const float*)d_in[1];
  const float* pe       = (const float*)d_in[2];
  const float* fc_w     = (const float*)d_in[3];
  const float* fc_b     = (const float*)d_in[4];
  const float* wg_w     = (const float*)d_in[5];
  const float* wg_b     = (const float*)d_in[6];
  const float* wq_w     = (const float*)d_in[7];
  const float* wq_b     = (const float*)d_in[8];
  const float* wk_w     = (const float*)d_in[9];
  const float* wk_b     = (const float*)d_in[10];
  const float* wv_w     = (const float*)d_in[11];
  const float* wv_b     = (const float*)d_in[12];

  char* ws = (char*)d_ws;
  unsigned short* Xb  = (unsigned short*)(ws);              // [3072][1024] bf16 (ref;sup)
  unsigned short* FCW = (unsigned short*)(ws + 6291456);    // [1024][1024]
  unsigned short* WQB = (unsigned short*)(ws + 8388608);
  unsigned short* WKB = (unsigned short*)(ws + 10485760);
  unsigned short* WVB = (unsigned short*)(ws + 12582912);
  unsigned short* RS  = (unsigned short*)(ws + 14680064);   // [3072][1024] relu(fc)
  unsigned short* QG  = (unsigned short*)(ws + 20971520);   // [16][2048][64]
  unsigned short* KG  = (unsigned short*)(ws + 25165824);   // [16][1024][64]
  unsigned short* SVT = (unsigned short*)(ws + 27262976);   // [16][64][1024]
  unsigned short* SC  = (unsigned short*)(ws + 29360128);   // [16][2048][1024] scores->P
  float*          RF  = (float*)(ws + 96468992);            // [2048][1024] fp32 R

  // bf16 conversions
  cvt_kernel<<<1024, 256, 0, stream>>>(ref_feat, Xb, 2097152);
  cvt_kernel<<<512, 256, 0, stream>>>(sup_feat, Xb + 2097152, 1048576);
  cvt_kernel<<<512, 256, 0, stream>>>(fc_w, FCW, 1048576);
  cvt_kernel<<<512, 256, 0, stream>>>(wq_w, WQB, 1048576);
  cvt_kernel<<<512, 256, 0, stream>>>(wk_w, WKB, 1048576);
  cvt_kernel<<<512, 256, 0, stream>>>(wv_w, WVB, 1048576);

  // fc layer: RS = relu(X @ fc_w^T + fc_b), fp32 copy of ref rows to RF
  gemm_nt<2, 2, 0><<<dim3(24, 8, 1), 256, 0, stream>>>(
      Xb, FCW, RS, fc_b, RF, nullptr, 3072, 1024, 1024, 1024, 0, 0);
  // Q = R @ wq^T + b -> [16][2048][64]
  gemm_nt<2, 2, 1><<<dim3(16, 8, 1), 256, 0, stream>>>(
      RS, WQB, QG, wq_b, nullptr, nullptr, 2048, 1024, 1024, 1024, 0, 0);
  // K = S @ wk^T + b -> [16][1024][64]
  gemm_nt<2, 2, 1><<<dim3(8, 8, 1), 256, 0, stream>>>(
      RS + 2097152, WKB, KG, wk_b, nullptr, nullptr, 1024, 1024, 1024, 1024, 0, 0);
  // SV = S @ wv^T -> transposed [16][64][1024]
  gemm_nt<2, 2, 2><<<dim3(8, 8, 1), 256, 0, stream>>>(
      RS + 2097152, WVB, SVT, nullptr, nullptr, nullptr, 1024, 1024, 1024, 1024, 0, 0);
  // scores_g = (Q_g @ K_g^T) * log2(e)/8 -> bf16 [16][2048][1024]
  gemm_nt<2, 2, 3><<<dim3(16, 8, 16), 256, 0, stream>>>(
      QG, KG, SC, nullptr, nullptr, nullptr, 2048, 64, 64, 64, 131072, 65536);
  // fused position bias + softmax (streams 512MB pe), P in-place
  pe_softmax<<<2048, 256, 0, stream>>>(pe, wg_w, wg_b, SC);
  // attention_g = P_g @ SV_g ; out = R + attn + wv_b
  gemm_nt<2, 1, 4><<<dim3(16, 1, 16), 128, 0, stream>>>(
      SC, SVT, d_out, nullptr, RF, wv_b, 2048, 1024, 1024, 1024, 2097152, 65536);
}

// Round 3
// 280.560 us; speedup vs baseline: 1.3320x; 1.3320x over previous
//
#include <hip/hip_runtime.h>

typedef __attribute__((ext_vector_type(8))) short short8;   // 8 bf16
typedef __attribute__((ext_vector_type(4))) float f32x4;    // MFMA acc

__device__ __forceinline__ unsigned short bf16r(float f) {
  unsigned int u = __float_as_uint(f);
  u = (u + 0x7FFFu + ((u >> 16) & 1u)) >> 16;
  return (unsigned short)u;
}
__device__ __forceinline__ float bf2f(unsigned short h) {
  return __uint_as_float(((unsigned int)h) << 16);
}
__device__ __forceinline__ unsigned int pk2(float a, float b) {
  return (unsigned int)bf16r(a) | ((unsigned int)bf16r(b) << 16);
}

// async 16B global->LDS (dest is wave-uniform base + lane*16)
__device__ __forceinline__ void gload16(const unsigned short* g, unsigned short* l) {
  __builtin_amdgcn_global_load_lds(
      (const __attribute__((address_space(1))) unsigned int*)g,
      (__attribute__((address_space(3))) unsigned int*)l, 16, 0, 0);
}

// Stage a 128x32 bf16 tile (8KB) into LDS, XOR-swizzled chunks.
// Physical chunk p of row r holds logical chunk p ^ ((r>>2)&3).
// Thread t covers linear bytes t*16 and t*16+4096 (linear dest, pre-swizzled src).
__device__ __forceinline__ void stage_tile(const unsigned short* __restrict__ gsrc, int ld,
                                           int k0, unsigned short* Ls, int t) {
  const int w = t >> 6;
  const int o0 = t * 16;
  const int r0 = o0 >> 6;
  const int c0 = ((((o0 >> 4) & 3) ^ ((r0 >> 2) & 3)) << 3);
  const int r1 = r0 + 64;
  const int c1 = ((((o0 >> 4) & 3) ^ ((r1 >> 2) & 3)) << 3);
  gload16(gsrc + (long)r0 * ld + k0 + c0, Ls + w * 512);
  gload16(gsrc + (long)r1 * ld + k0 + c1, Ls + 2048 + w * 512);
}

// LDS-staged K-loop: 128x128 tile, 4 waves (2x2), 4x4 16x16x32 frags / wave.
// SWAPPED mfma(b,a): acc reg ri <-> B-row (output col), lane&15 <-> A-row.
__device__ __forceinline__ void kloop(const unsigned short* __restrict__ A,
                                      const unsigned short* __restrict__ B,
                                      int lda, int ldb, int K,
                                      unsigned short* As, unsigned short* Bs,
                                      int t, f32x4 acc[4][4]) {
  const int lane = t & 63;
  const int w = t >> 6;
  const int wr = w >> 1, wc = w & 1;
  const int ra = lane & 15;
  const int ch = ((lane >> 4) ^ (ra >> 2)) << 3;   // swizzled element offset in row
  for (int k0 = 0; k0 < K; k0 += 32) {
    __syncthreads();                 // all waves done reading previous tile
    stage_tile(A, lda, k0, As, t);
    stage_tile(B, ldb, k0, Bs, t);
    __syncthreads();                 // drains vmcnt: tiles ready
    short8 a[4], b[4];
#pragma unroll
    for (int i = 0; i < 4; ++i)
      a[i] = *(const short8*)(As + (wr * 64 + i * 16 + ra) * 32 + ch);
#pragma unroll
    for (int j = 0; j < 4; ++j)
      b[j] = *(const short8*)(Bs + (wc * 64 + j * 16 + ra) * 32 + ch);
#pragma unroll
    for (int i = 0; i < 4; ++i)
#pragma unroll
      for (int j = 0; j < 4; ++j)
        acc[i][j] = __builtin_amdgcn_mfma_f32_16x16x32_bf16(b[j], a[i], acc[i][j], 0, 0, 0);
  }
}

// ---------------- fused fp32->bf16 convert of all inputs ----------------
__global__ __launch_bounds__(256)
void cvt_all(const float* __restrict__ ref, const float* __restrict__ sup,
             const float* __restrict__ fcw, const float* __restrict__ wq,
             const float* __restrict__ wk, const float* __restrict__ wv,
             unsigned short* __restrict__ Xb, unsigned short* __restrict__ FCW,
             unsigned short* __restrict__ WQB, unsigned short* __restrict__ WKB,
             unsigned short* __restrict__ WVB) {
  long u = ((long)blockIdx.x * 256 + threadIdx.x) * 4;
  const float* src; unsigned short* dst;
  if (u < 2097152)      { src = ref + u;             dst = Xb + u; }
  else if (u < 3145728) { src = sup + (u - 2097152); dst = Xb + u; }
  else if (u < 4194304) { src = fcw + (u - 3145728); dst = FCW + (u - 3145728); }
  else if (u < 5242880) { src = wq + (u - 4194304);  dst = WQB + (u - 4194304); }
  else if (u < 6291456) { src = wk + (u - 5242880);  dst = WKB + (u - 5242880); }
  else                  { src = wv + (u - 6291456);  dst = WVB + (u - 6291456); }
  float4 v = *(const float4*)src;
  ushort4 o;
  o.x = bf16r(v.x); o.y = bf16r(v.y); o.z = bf16r(v.z); o.w = bf16r(v.w);
  *(ushort4*)dst = o;
}

// ---------------- fc: RS = relu(X @ fcW^T + b), bf16 out ----------------
__global__ __launch_bounds__(256)
void gemm_fc(const unsigned short* __restrict__ X, const unsigned short* __restrict__ W,
             const float* __restrict__ bias, unsigned short* __restrict__ RS) {
  __shared__ unsigned short As[4096], Bs[4096];
  const int t = threadIdx.x, lane = t & 63, w = t >> 6;
  const int wr = w >> 1, wc = w & 1;
  const int row0 = blockIdx.x * 128, col0 = blockIdx.y * 128;
  f32x4 acc[4][4] = {};
  kloop(X + (long)row0 * 1024, W + (long)col0 * 1024, 1024, 1024, 1024, As, Bs, t, acc);
  const int rl = lane & 15, q4 = (lane >> 4) << 2;
#pragma unroll
  for (int i = 0; i < 4; ++i) {
    int rr = row0 + wr * 64 + i * 16 + rl;
#pragma unroll
    for (int j = 0; j < 4; ++j) {
      int cc = col0 + wc * 64 + j * 16 + q4;
      float4 bb = *(const float4*)(bias + cc);
      float v0 = fmaxf(acc[i][j][0] + bb.x, 0.f);
      float v1 = fmaxf(acc[i][j][1] + bb.y, 0.f);
      float v2 = fmaxf(acc[i][j][2] + bb.z, 0.f);
      float v3 = fmaxf(acc[i][j][3] + bb.w, 0.f);
      uint2 o; o.x = pk2(v0, v1); o.y = pk2(v2, v3);
      *(uint2*)(RS + (long)rr * 1024 + cc) = o;
    }
  }
}

// ---------------- batched Q/K/SV: z=0 Q, z=1 K, z=2 SV^T ----------------
__global__ __launch_bounds__(256)
void gemm_qkv(const unsigned short* __restrict__ RS,
              const unsigned short* __restrict__ WQ, const unsigned short* __restrict__ WK,
              const unsigned short* __restrict__ WV,
              const float* __restrict__ qb, const float* __restrict__ kb,
              unsigned short* __restrict__ QG, unsigned short* __restrict__ KG,
              unsigned short* __restrict__ SVT) {
  const int z = blockIdx.z;
  const unsigned short* A; const unsigned short* B; int M;
  if (z == 0)      { A = RS;           B = WQ; M = 2048; }
  else if (z == 1) { A = RS + 2097152; B = WK; M = 1024; }
  else             { A = RS + 2097152; B = WV; M = 1024; }
  const int row0 = blockIdx.x * 128;
  if (row0 >= M) return;
  const int col0 = blockIdx.y * 128;
  __shared__ unsigned short As[4096], Bs[4096];
  const int t = threadIdx.x, lane = t & 63, w = t >> 6;
  const int wr = w >> 1, wc = w & 1;
  f32x4 acc[4][4] = {};
  kloop(A + (long)row0 * 1024, B + (long)col0 * 1024, 1024, 1024, 1024, As, Bs, t, acc);
  const int rl = lane & 15, q4 = (lane >> 4) << 2;
  if (z == 2) {
#pragma unroll
    for (int i = 0; i < 4; ++i) {
      int rr = row0 + wr * 64 + i * 16 + rl;           // sup row = SVT col
#pragma unroll
      for (int j = 0; j < 4; ++j) {
        int cg = col0 + wc * 64 + j * 16 + q4;         // output channel
#pragma unroll
        for (int ri = 0; ri < 4; ++ri) {
          int gg = (cg + ri) >> 6, jj = (cg + ri) & 63;
          SVT[(long)gg * 65536 + (long)jj * 1024 + rr] = bf16r(acc[i][j][ri]);
        }
      }
    }
  } else {
    const float* bias = z ? kb : qb;
    unsigned short* out = z ? KG : QG;
    const long gs = z ? 65536 : 131072;
#pragma unroll
    for (int i = 0; i < 4; ++i) {
      int rr = row0 + wr * 64 + i * 16 + rl;
#pragma unroll
      for (int j = 0; j < 4; ++j) {
        int cc = col0 + wc * 64 + j * 16 + q4;
        float4 bb = *(const float4*)(bias + cc);
        int gg = cc >> 6, jj = cc & 63;
        uint2 o;
        o.x = pk2(acc[i][j][0] + bb.x, acc[i][j][1] + bb.y);
        o.y = pk2(acc[i][j][2] + bb.z, acc[i][j][3] + bb.w);
        *(uint2*)(out + (long)gg * gs + (long)rr * 64 + jj) = o;
      }
    }
  }
}

// ---------------- scores_g = (Q_g @ K_g^T) * log2(e)/8, bf16 ----------------
__global__ __launch_bounds__(256)
void gemm_scores(const unsigned short* __restrict__ QG, const unsigned short* __restrict__ KG,
                 unsigned short* __restrict__ SC) {
  const int g = blockIdx.z;
  const unsigned short* A = QG + (long)g * 131072;   // [2048][64]
  const unsigned short* B = KG + (long)g * 65536;    // [1024][64]
  const int t = threadIdx.x, lane = t & 63, w = t >> 6;
  const int wr = w >> 1, wc = w & 1;
  const int row0 = blockIdx.x * 128 + wr * 64, col0 = blockIdx.y * 128 + wc * 64;
  const int ra = lane & 15, kg8 = (lane >> 4) << 3;
  f32x4 acc[4][4] = {};
#pragma unroll
  for (int k0 = 0; k0 < 64; k0 += 32) {
    short8 a[4], b[4];
#pragma unroll
    for (int i = 0; i < 4; ++i)
      a[i] = *(const short8*)(A + (long)(row0 + i * 16 + ra) * 64 + k0 + kg8);
#pragma unroll
    for (int j = 0; j < 4; ++j)
      b[j] = *(const short8*)(B + (long)(col0 + j * 16 + ra) * 64 + k0 + kg8);
#pragma unroll
    for (int i = 0; i < 4; ++i)
#pragma unroll
      for (int j = 0; j < 4; ++j)
        acc[i][j] = __builtin_amdgcn_mfma_f32_16x16x32_bf16(b[j], a[i], acc[i][j], 0, 0, 0);
  }
  const int rl = lane & 15, q4 = (lane >> 4) << 2;
  const float s = 0.18033688011112042f;   // log2(e)/8
#pragma unroll
  for (int i = 0; i < 4; ++i) {
    int rr = row0 + i * 16 + rl;
#pragma unroll
    for (int j = 0; j < 4; ++j) {
      int cc = col0 + j * 16 + q4;
      uint2 o;
      o.x = pk2(acc[i][j][0] * s, acc[i][j][1] * s);
      o.y = pk2(acc[i][j][2] * s, acc[i][j][3] * s);
      *(uint2*)(SC + (long)g * 2097152 + (long)rr * 1024 + cc) = o;
    }
  }
}

// ---------------- fused position-bias conv + softmax (streams 512MB pe) ----
__global__ __launch_bounds__(256)
void pe_softmax(const float* __restrict__ pe, const float* __restrict__ wgw,
                const float* __restrict__ wgb, unsigned short* __restrict__ Sc) {
  const int n = blockIdx.x;
  const int t = threadIdx.x;
  const int lane = t & 63;
  const int wid = t >> 6;
  __shared__ __align__(16) float wgT[64][16];
  __shared__ float redM[4][16];
  __shared__ float redS[4][16];
  for (int i = t; i < 1024; i += 256) wgT[i & 63][i >> 6] = wgw[i];
  __syncthreads();

  float acc[64];
#pragma unroll
  for (int g = 0; g < 16; ++g) {
    float bb = wgb[g];
#pragma unroll
    for (int mm = 0; mm < 4; ++mm) acc[g * 4 + mm] = bb;
  }

  const float* pebase = pe + (long)n * 1024 + t * 4;
#pragma unroll 2
  for (int e = 0; e < 64; ++e) {
    float4 p = *(const float4*)(pebase + (long)e * 2097152);
    const f32x4* wrow = (const f32x4*)(&wgT[e][0]);
    f32x4 w0 = wrow[0], w1 = wrow[1], w2 = wrow[2], w3 = wrow[3];
    float wg16[16] = {w0[0], w0[1], w0[2], w0[3], w1[0], w1[1], w1[2], w1[3],
                      w2[0], w2[1], w2[2], w2[3], w3[0], w3[1], w3[2], w3[3]};
#pragma unroll
    for (int g = 0; g < 16; ++g) {
      acc[g * 4 + 0] = fmaf(wg16[g], p.x, acc[g * 4 + 0]);
      acc[g * 4 + 1] = fmaf(wg16[g], p.y, acc[g * 4 + 1]);
      acc[g * 4 + 2] = fmaf(wg16[g], p.z, acc[g * 4 + 2]);
      acc[g * 4 + 3] = fmaf(wg16[g], p.w, acc[g * 4 + 3]);
    }
  }

#pragma unroll
  for (int g = 0; g < 16; ++g) {
    ushort4 s4 = *(const ushort4*)(Sc + (long)g * 2097152 + (long)n * 1024 + t * 4);
    acc[g * 4 + 0] = __builtin_amdgcn_logf(fmaxf(acc[g * 4 + 0], 0.f) + 1e-6f) + bf2f(s4.x);
    acc[g * 4 + 1] = __builtin_amdgcn_logf(fmaxf(acc[g * 4 + 1], 0.f) + 1e-6f) + bf2f(s4.y);
    acc[g * 4 + 2] = __builtin_amdgcn_logf(fmaxf(acc[g * 4 + 2], 0.f) + 1e-6f) + bf2f(s4.z);
    acc[g * 4 + 3] = __builtin_amdgcn_logf(fmaxf(acc[g * 4 + 3], 0.f) + 1e-6f) + bf2f(s4.w);
  }

  float gmax[16];
#pragma unroll
  for (int g = 0; g < 16; ++g) {
    float m = fmaxf(fmaxf(acc[g * 4 + 0], acc[g * 4 + 1]),
                    fmaxf(acc[g * 4 + 2], acc[g * 4 + 3]));
#pragma unroll
    for (int off = 32; off >= 1; off >>= 1) m = fmaxf(m, __shfl_xor(m, off));
    if (lane == 0) redM[wid][g] = m;
  }
  __syncthreads();
#pragma unroll
  for (int g = 0; g < 16; ++g)
    gmax[g] = fmaxf(fmaxf(redM[0][g], redM[1][g]), fmaxf(redM[2][g], redM[3][g]));

#pragma unroll
  for (int g = 0; g < 16; ++g) {
    float s = __builtin_amdgcn_exp2f(acc[g * 4 + 0] - gmax[g])
            + __builtin_amdgcn_exp2f(acc[g * 4 + 1] - gmax[g])
            + __builtin_amdgcn_exp2f(acc[g * 4 + 2] - gmax[g])
            + __builtin_amdgcn_exp2f(acc[g * 4 + 3] - gmax[g]);
#pragma unroll
    for (int off = 32; off >= 1; off >>= 1) s += __shfl_xor(s, off);
    if (lane == 0) redS[wid][g] = s;
  }
  __syncthreads();

#pragma unroll
  for (int g = 0; g < 16; ++g) {
    float sum = redS[0][g] + redS[1][g] + redS[2][g] + redS[3][g];
    float rs = __builtin_amdgcn_rcpf(sum);
    ushort4 o;
    o.x = bf16r(__builtin_amdgcn_exp2f(acc[g * 4 + 0] - gmax[g]) * rs);
    o.y = bf16r(__builtin_amdgcn_exp2f(acc[g * 4 + 1] - gmax[g]) * rs);
    o.z = bf16r(__builtin_amdgcn_exp2f(acc[g * 4 + 2] - gmax[g]) * rs);
    o.w = bf16r(__builtin_amdgcn_exp2f(acc[g * 4 + 3] - gmax[g]) * rs);
    *(ushort4*)(Sc + (long)g * 2097152 + (long)n * 1024 + t * 4) = o;
  }
}

// ---------------- out = P_g @ SV_g^T + wv_b + R (fp32) ----------------
__global__ __launch_bounds__(128)
void gemm_final(const unsigned short* __restrict__ SC, const unsigned short* __restrict__ SVT,
                const unsigned short* __restrict__ RS, const float* __restrict__ wvb,
                float* __restrict__ out) {
  const int g = blockIdx.z;
  const unsigned short* A = SC + (long)g * 2097152;  // [2048][1024]
  const unsigned short* B = SVT + (long)g * 65536;   // [64][1024]
  const int t = threadIdx.x, lane = t & 63, w = t >> 6;   // 2 waves
  const int row0 = blockIdx.x * 128 + w * 64;
  const int ra = lane & 15, kg8 = (lane >> 4) << 3;
  f32x4 acc[4][4] = {};
  for (int k0 = 0; k0 < 1024; k0 += 32) {
    short8 a[4], b[4];
#pragma unroll
    for (int i = 0; i < 4; ++i)
      a[i] = *(const short8*)(A + (long)(row0 + i * 16 + ra) * 1024 + k0 + kg8);
#pragma unroll
    for (int j = 0; j < 4; ++j)
      b[j] = *(const short8*)(B + (long)(j * 16 + ra) * 1024 + k0 + kg8);
#pragma unroll
    for (int i = 0; i < 4; ++i)
#pragma unroll
      for (int j = 0; j < 4; ++j)
        acc[i][j] = __builtin_amdgcn_mfma_f32_16x16x32_bf16(b[j], a[i], acc[i][j], 0, 0, 0);
  }
  const int rl = lane & 15, q4 = (lane >> 4) << 2;
#pragma unroll
  for (int i = 0; i < 4; ++i) {
    int rr = row0 + i * 16 + rl;
#pragma unroll
    for (int j = 0; j < 4; ++j) {
      int oc = g * 64 + j * 16 + q4;
      float4 w4 = *(const float4*)(wvb + oc);
      ushort4 r4 = *(const ushort4*)(RS + (long)rr * 1024 + oc);
      float4 o;
      o.x = acc[i][j][0] + w4.x + bf2f(r4.x);
      o.y = acc[i][j][1] + w4.y + bf2f(r4.y);
      o.z = acc[i][j][2] + w4.z + bf2f(r4.z);
      o.w = acc[i][j][3] + w4.w + bf2f(r4.w);
      *(float4*)(out + (long)rr * 1024 + oc) = o;
    }
  }
}

extern "C" void kernel_launch(void* const* d_in, const int* in_sizes, int n_in,
                              void* d_out, int out_size, void* d_ws, size_t ws_size,
                              hipStream_t stream) {
  const float* ref_feat = (const float*)d_in[0];
  const float* sup_feat = (const float*)d_in[1];
  const float* pe       = (const float*)d_in[2];
  const float* fc_w     = (const float*)d_in[3];
  const float* fc_b     = (const float*)d_in[4];
  const float* wg_w     = (const float*)d_in[5];
  const float* wg_b     = (const float*)d_in[6];
  const float* wq_w     = (const float*)d_in[7];
  const float* wq_b     = (const float*)d_in[8];
  const float* wk_w     = (const float*)d_in[9];
  const float* wk_b     = (const float*)d_in[10];
  const float* wv_w     = (const float*)d_in[11];
  const float* wv_b     = (const float*)d_in[12];

  char* ws = (char*)d_ws;
  unsigned short* Xb  = (unsigned short*)(ws);              // [3072][1024]
  unsigned short* FCW = (unsigned short*)(ws + 6291456);
  unsigned short* WQB = (unsigned short*)(ws + 8388608);
  unsigned short* WKB = (unsigned short*)(ws + 10485760);
  unsigned short* WVB = (unsigned short*)(ws + 12582912);
  unsigned short* RS  = (unsigned short*)(ws + 14680064);   // [3072][1024] relu(fc) bf16
  unsigned short* QG  = (unsigned short*)(ws + 20971520);   // [16][2048][64]
  unsigned short* KG  = (unsigned short*)(ws + 25165824);   // [16][1024][64]
  unsigned short* SVT = (unsigned short*)(ws + 27262976);   // [16][64][1024]
  unsigned short* SC  = (unsigned short*)(ws + 29360128);   // [16][2048][1024]

  cvt_all<<<7168, 256, 0, stream>>>(ref_feat, sup_feat, fc_w, wq_w, wk_w, wv_w,
                                    Xb, FCW, WQB, WKB, WVB);
  gemm_fc<<<dim3(24, 8), 256, 0, stream>>>(Xb, FCW, fc_b, RS);
  gemm_qkv<<<dim3(16, 8, 3), 256, 0, stream>>>(RS, WQB, WKB, WVB, wq_b, wk_b, QG, KG, SVT);
  gemm_scores<<<dim3(16, 8, 16), 256, 0, stream>>>(QG, KG, SC);
  pe_softmax<<<2048, 256, 0, stream>>>(pe, wg_w, wg_b, SC);
  gemm_final<<<dim3(16, 1, 16), 128, 0, stream>>>(SC, SVT, RS, wv_b, (float*)d_out);
}

// Round 4
// 280.188 us; speedup vs baseline: 1.3338x; 1.0013x over previous
//
#include <hip/hip_runtime.h>

typedef __attribute__((ext_vector_type(8))) short short8;   // 8 bf16
typedef __attribute__((ext_vector_type(4))) float f32x4;    // MFMA acc

__device__ __forceinline__ unsigned short bf16r(float f) {
  unsigned int u = __float_as_uint(f);
  u = (u + 0x7FFFu + ((u >> 16) & 1u)) >> 16;
  return (unsigned short)u;
}
__device__ __forceinline__ float bf2f(unsigned short h) {
  return __uint_as_float(((unsigned int)h) << 16);
}
__device__ __forceinline__ unsigned int pk2(float a, float b) {
  return (unsigned int)bf16r(a) | ((unsigned int)bf16r(b) << 16);
}

// async 16B global->LDS (dest is wave-uniform base + lane*16)
__device__ __forceinline__ void gload16(const unsigned short* g, unsigned short* l) {
  __builtin_amdgcn_global_load_lds(
      (const __attribute__((address_space(1))) unsigned int*)g,
      (__attribute__((address_space(3))) unsigned int*)l, 16, 0, 0);
}

// Stage a 128x32 bf16 tile (8KB) into LDS, XOR-swizzled chunks.
// Physical chunk p of row r holds logical chunk p ^ ((r>>2)&3).
// Thread t covers linear bytes t*16 and t*16+4096 (linear dest, pre-swizzled src).
__device__ __forceinline__ void stage_tile(const unsigned short* __restrict__ gsrc, int ld,
                                           int k0, unsigned short* Ls, int t) {
  const int w = t >> 6;
  const int o0 = t * 16;
  const int r0 = o0 >> 6;
  const int c0 = ((((o0 >> 4) & 3) ^ ((r0 >> 2) & 3)) << 3);
  const int r1 = r0 + 64;
  const int c1 = ((((o0 >> 4) & 3) ^ ((r1 >> 2) & 3)) << 3);
  gload16(gsrc + (long)r0 * ld + k0 + c0, Ls + w * 512);
  gload16(gsrc + (long)r1 * ld + k0 + c1, Ls + 2048 + w * 512);
}

// Double-buffered LDS K-loop (2-phase): STAGE(next) || ds_read+MFMA(cur),
// ONE barrier per K-step (its vmcnt/lgkm drain lands after compute, so the
// next tile's load latency hides under this tile's MFMA phase).
// 128x128 tile, 4 waves (2x2), 4x4 16x16x32 frags / wave.
// SWAPPED mfma(b,a): acc reg ri <-> B-row (output col), lane&15 <-> A-row.
__device__ __forceinline__ void kloop(const unsigned short* __restrict__ A,
                                      const unsigned short* __restrict__ B,
                                      int lda, int ldb, int K,
                                      unsigned short* As, unsigned short* Bs,  // [2][4096] each
                                      int t, f32x4 acc[4][4]) {
  const int lane = t & 63;
  const int w = t >> 6;
  const int wr = w >> 1, wc = w & 1;
  const int ra = lane & 15;
  const int ch = ((lane >> 4) ^ (ra >> 2)) << 3;   // swizzled element offset in row
  stage_tile(A, lda, 0, As, t);
  stage_tile(B, ldb, 0, Bs, t);
  __syncthreads();                 // tile 0 ready
  for (int k0 = 0; k0 < K; k0 += 32) {
    const int p = (k0 >> 5) & 1;
    unsigned short* Ac = As + p * 4096;
    unsigned short* Bc = Bs + p * 4096;
    if (k0 + 32 < K) {             // issue next tile's loads (fly during MFMA)
      stage_tile(A, lda, k0 + 32, As + (p ^ 1) * 4096, t);
      stage_tile(B, ldb, k0 + 32, Bs + (p ^ 1) * 4096, t);
    }
    short8 a[4], b[4];
#pragma unroll
    for (int i = 0; i < 4; ++i)
      a[i] = *(const short8*)(Ac + (wr * 64 + i * 16 + ra) * 32 + ch);
#pragma unroll
    for (int j = 0; j < 4; ++j)
      b[j] = *(const short8*)(Bc + (wc * 64 + j * 16 + ra) * 32 + ch);
#pragma unroll
    for (int i = 0; i < 4; ++i)
#pragma unroll
      for (int j = 0; j < 4; ++j)
        acc[i][j] = __builtin_amdgcn_mfma_f32_16x16x32_bf16(b[j], a[i], acc[i][j], 0, 0, 0);
    __syncthreads();               // drains: next tile staged, all waves done reading cur
  }
}

// ---------------- fused fp32->bf16 convert of all inputs ----------------
__global__ __launch_bounds__(256)
void cvt_all(const float* __restrict__ ref, const float* __restrict__ sup,
             const float* __restrict__ fcw, const float* __restrict__ wq,
             const float* __restrict__ wk, const float* __restrict__ wv,
             unsigned short* __restrict__ Xb, unsigned short* __restrict__ FCW,
             unsigned short* __restrict__ WQB, unsigned short* __restrict__ WKB,
             unsigned short* __restrict__ WVB) {
  long u = ((long)blockIdx.x * 256 + threadIdx.x) * 4;
  const float* src; unsigned short* dst;
  if (u < 2097152)      { src = ref + u;             dst = Xb + u; }
  else if (u < 3145728) { src = sup + (u - 2097152); dst = Xb + u; }
  else if (u < 4194304) { src = fcw + (u - 3145728); dst = FCW + (u - 3145728); }
  else if (u < 5242880) { src = wq + (u - 4194304);  dst = WQB + (u - 4194304); }
  else if (u < 6291456) { src = wk + (u - 5242880);  dst = WKB + (u - 5242880); }
  else                  { src = wv + (u - 6291456);  dst = WVB + (u - 6291456); }
  float4 v = *(const float4*)src;
  ushort4 o;
  o.x = bf16r(v.x); o.y = bf16r(v.y); o.z = bf16r(v.z); o.w = bf16r(v.w);
  *(ushort4*)dst = o;
}

// ---------------- fc: RS = relu(X @ fcW^T + b), bf16 out ----------------
__global__ __launch_bounds__(256)
void gemm_fc(const unsigned short* __restrict__ X, const unsigned short* __restrict__ W,
             const float* __restrict__ bias, unsigned short* __restrict__ RS) {
  __shared__ unsigned short As[8192], Bs[8192];
  const int t = threadIdx.x, lane = t & 63, w = t >> 6;
  const int wr = w >> 1, wc = w & 1;
  const int row0 = blockIdx.x * 128, col0 = blockIdx.y * 128;
  f32x4 acc[4][4] = {};
  kloop(X + (long)row0 * 1024, W + (long)col0 * 1024, 1024, 1024, 1024, As, Bs, t, acc);
  const int rl = lane & 15, q4 = (lane >> 4) << 2;
#pragma unroll
  for (int i = 0; i < 4; ++i) {
    int rr = row0 + wr * 64 + i * 16 + rl;
#pragma unroll
    for (int j = 0; j < 4; ++j) {
      int cc = col0 + wc * 64 + j * 16 + q4;
      float4 bb = *(const float4*)(bias + cc);
      float v0 = fmaxf(acc[i][j][0] + bb.x, 0.f);
      float v1 = fmaxf(acc[i][j][1] + bb.y, 0.f);
      float v2 = fmaxf(acc[i][j][2] + bb.z, 0.f);
      float v3 = fmaxf(acc[i][j][3] + bb.w, 0.f);
      uint2 o; o.x = pk2(v0, v1); o.y = pk2(v2, v3);
      *(uint2*)(RS + (long)rr * 1024 + cc) = o;
    }
  }
}

// ---------------- batched Q/K/SV: z=0 Q, z=1 K, z=2 SV^T ----------------
__global__ __launch_bounds__(256)
void gemm_qkv(const unsigned short* __restrict__ RS,
              const unsigned short* __restrict__ WQ, const unsigned short* __restrict__ WK,
              const unsigned short* __restrict__ WV,
              const float* __restrict__ qb, const float* __restrict__ kb,
              unsigned short* __restrict__ QG, unsigned short* __restrict__ KG,
              unsigned short* __restrict__ SVT) {
  const int z = blockIdx.z;
  const unsigned short* A; const unsigned short* B; int M;
  if (z == 0)      { A = RS;           B = WQ; M = 2048; }
  else if (z == 1) { A = RS + 2097152; B = WK; M = 1024; }
  else             { A = RS + 2097152; B = WV; M = 1024; }
  const int row0 = blockIdx.x * 128;
  if (row0 >= M) return;
  const int col0 = blockIdx.y * 128;
  __shared__ unsigned short As[8192], Bs[8192];
  const int t = threadIdx.x, lane = t & 63, w = t >> 6;
  const int wr = w >> 1, wc = w & 1;
  f32x4 acc[4][4] = {};
  kloop(A + (long)row0 * 1024, B + (long)col0 * 1024, 1024, 1024, 1024, As, Bs, t, acc);
  const int rl = lane & 15, q4 = (lane >> 4) << 2;
  if (z == 2) {
#pragma unroll
    for (int i = 0; i < 4; ++i) {
      int rr = row0 + wr * 64 + i * 16 + rl;           // sup row = SVT col
#pragma unroll
      for (int j = 0; j < 4; ++j) {
        int cg = col0 + wc * 64 + j * 16 + q4;         // output channel
#pragma unroll
        for (int ri = 0; ri < 4; ++ri) {
          int gg = (cg + ri) >> 6, jj = (cg + ri) & 63;
          SVT[(long)gg * 65536 + (long)jj * 1024 + rr] = bf16r(acc[i][j][ri]);
        }
      }
    }
  } else {
    const float* bias = z ? kb : qb;
    unsigned short* out = z ? KG : QG;
    const long gs = z ? 65536 : 131072;
#pragma unroll
    for (int i = 0; i < 4; ++i) {
      int rr = row0 + wr * 64 + i * 16 + rl;
#pragma unroll
      for (int j = 0; j < 4; ++j) {
        int cc = col0 + wc * 64 + j * 16 + q4;
        float4 bb = *(const float4*)(bias + cc);
        int gg = cc >> 6, jj = cc & 63;
        uint2 o;
        o.x = pk2(acc[i][j][0] + bb.x, acc[i][j][1] + bb.y);
        o.y = pk2(acc[i][j][2] + bb.z, acc[i][j][3] + bb.w);
        *(uint2*)(out + (long)gg * gs + (long)rr * 64 + jj) = o;
      }
    }
  }
}

// ---------------- scores_g = (Q_g @ K_g^T) * log2(e)/8, bf16 ----------------
__global__ __launch_bounds__(256)
void gemm_scores(const unsigned short* __restrict__ QG, const unsigned short* __restrict__ KG,
                 unsigned short* __restrict__ SC) {
  const int g = blockIdx.z;
  const unsigned short* A = QG + (long)g * 131072;   // [2048][64]
  const unsigned short* B = KG + (long)g * 65536;    // [1024][64]
  const int t = threadIdx.x, lane = t & 63, w = t >> 6;
  const int wr = w >> 1, wc = w & 1;
  const int row0 = blockIdx.x * 128 + wr * 64, col0 = blockIdx.y * 128 + wc * 64;
  const int ra = lane & 15, kg8 = (lane >> 4) << 3;
  f32x4 acc[4][4] = {};
#pragma unroll
  for (int k0 = 0; k0 < 64; k0 += 32) {
    short8 a[4], b[4];
#pragma unroll
    for (int i = 0; i < 4; ++i)
      a[i] = *(const short8*)(A + (long)(row0 + i * 16 + ra) * 64 + k0 + kg8);
#pragma unroll
    for (int j = 0; j < 4; ++j)
      b[j] = *(const short8*)(B + (long)(col0 + j * 16 + ra) * 64 + k0 + kg8);
#pragma unroll
    for (int i = 0; i < 4; ++i)
#pragma unroll
      for (int j = 0; j < 4; ++j)
        acc[i][j] = __builtin_amdgcn_mfma_f32_16x16x32_bf16(b[j], a[i], acc[i][j], 0, 0, 0);
  }
  const int rl = lane & 15, q4 = (lane >> 4) << 2;
  const float s = 0.18033688011112042f;   // log2(e)/8
#pragma unroll
  for (int i = 0; i < 4; ++i) {
    int rr = row0 + i * 16 + rl;
#pragma unroll
    for (int j = 0; j < 4; ++j) {
      int cc = col0 + j * 16 + q4;
      uint2 o;
      o.x = pk2(acc[i][j][0] * s, acc[i][j][1] * s);
      o.y = pk2(acc[i][j][2] * s, acc[i][j][3] * s);
      *(uint2*)(SC + (long)g * 2097152 + (long)rr * 1024 + cc) = o;
    }
  }
}

// ---------------- fused position-bias conv + softmax (streams 512MB pe) ----
__global__ __launch_bounds__(256)
void pe_softmax(const float* __restrict__ pe, const float* __restrict__ wgw,
                const float* __restrict__ wgb, unsigned short* __restrict__ Sc) {
  const int n = blockIdx.x;
  const int t = threadIdx.x;
  const int lane = t & 63;
  const int wid = t >> 6;
  __shared__ __align__(16) float wgT[64][16];
  __shared__ float redM[4][16];
  __shared__ float redS[4][16];
  for (int i = t; i < 1024; i += 256) wgT[i & 63][i >> 6] = wgw[i];
  __syncthreads();

  float acc[64];
#pragma unroll
  for (int g = 0; g < 16; ++g) {
    float bb = wgb[g];
#pragma unroll
    for (int mm = 0; mm < 4; ++mm) acc[g * 4 + mm] = bb;
  }

  const float* pebase = pe + (long)n * 1024 + t * 4;
#pragma unroll 2
  for (int e = 0; e < 64; ++e) {
    float4 p = *(const float4*)(pebase + (long)e * 2097152);
    const f32x4* wrow = (const f32x4*)(&wgT[e][0]);
    f32x4 w0 = wrow[0], w1 = wrow[1], w2 = wrow[2], w3 = wrow[3];
    float wg16[16] = {w0[0], w0[1], w0[2], w0[3], w1[0], w1[1], w1[2], w1[3],
                      w2[0], w2[1], w2[2], w2[3], w3[0], w3[1], w3[2], w3[3]};
#pragma unroll
    for (int g = 0; g < 16; ++g) {
      acc[g * 4 + 0] = fmaf(wg16[g], p.x, acc[g * 4 + 0]);
      acc[g * 4 + 1] = fmaf(wg16[g], p.y, acc[g * 4 + 1]);
      acc[g * 4 + 2] = fmaf(wg16[g], p.z, acc[g * 4 + 2]);
      acc[g * 4 + 3] = fmaf(wg16[g], p.w, acc[g * 4 + 3]);
    }
  }

#pragma unroll
  for (int g = 0; g < 16; ++g) {
    ushort4 s4 = *(const ushort4*)(Sc + (long)g * 2097152 + (long)n * 1024 + t * 4);
    acc[g * 4 + 0] = __builtin_amdgcn_logf(fmaxf(acc[g * 4 + 0], 0.f) + 1e-6f) + bf2f(s4.x);
    acc[g * 4 + 1] = __builtin_amdgcn_logf(fmaxf(acc[g * 4 + 1], 0.f) + 1e-6f) + bf2f(s4.y);
    acc[g * 4 + 2] = __builtin_amdgcn_logf(fmaxf(acc[g * 4 + 2], 0.f) + 1e-6f) + bf2f(s4.z);
    acc[g * 4 + 3] = __builtin_amdgcn_logf(fmaxf(acc[g * 4 + 3], 0.f) + 1e-6f) + bf2f(s4.w);
  }

  float gmax[16];
#pragma unroll
  for (int g = 0; g < 16; ++g) {
    float m = fmaxf(fmaxf(acc[g * 4 + 0], acc[g * 4 + 1]),
                    fmaxf(acc[g * 4 + 2], acc[g * 4 + 3]));
#pragma unroll
    for (int off = 32; off >= 1; off >>= 1) m = fmaxf(m, __shfl_xor(m, off));
    if (lane == 0) redM[wid][g] = m;
  }
  __syncthreads();
#pragma unroll
  for (int g = 0; g < 16; ++g)
    gmax[g] = fmaxf(fmaxf(redM[0][g], redM[1][g]), fmaxf(redM[2][g], redM[3][g]));

#pragma unroll
  for (int g = 0; g < 16; ++g) {
    float s = __builtin_amdgcn_exp2f(acc[g * 4 + 0] - gmax[g])
            + __builtin_amdgcn_exp2f(acc[g * 4 + 1] - gmax[g])
            + __builtin_amdgcn_exp2f(acc[g * 4 + 2] - gmax[g])
            + __builtin_amdgcn_exp2f(acc[g * 4 + 3] - gmax[g]);
#pragma unroll
    for (int off = 32; off >= 1; off >>= 1) s += __shfl_xor(s, off);
    if (lane == 0) redS[wid][g] = s;
  }
  __syncthreads();

#pragma unroll
  for (int g = 0; g < 16; ++g) {
    float sum = redS[0][g] + redS[1][g] + redS[2][g] + redS[3][g];
    float rs = __builtin_amdgcn_rcpf(sum);
    ushort4 o;
    o.x = bf16r(__builtin_amdgcn_exp2f(acc[g * 4 + 0] - gmax[g]) * rs);
    o.y = bf16r(__builtin_amdgcn_exp2f(acc[g * 4 + 1] - gmax[g]) * rs);
    o.z = bf16r(__builtin_amdgcn_exp2f(acc[g * 4 + 2] - gmax[g]) * rs);
    o.w = bf16r(__builtin_amdgcn_exp2f(acc[g * 4 + 3] - gmax[g]) * rs);
    *(ushort4*)(Sc + (long)g * 2097152 + (long)n * 1024 + t * 4) = o;
  }
}

// ---------------- out = P_g @ SV_g^T + wv_b + R (fp32) ----------------
// Register-double-buffered K-loop (manual unroll-2, static indexing).
__global__ __launch_bounds__(128)
void gemm_final(const unsigned short* __restrict__ SC, const unsigned short* __restrict__ SVT,
                const unsigned short* __restrict__ RS, const float* __restrict__ wvb,
                float* __restrict__ out) {
  const int g = blockIdx.z;
  const unsigned short* A = SC + (long)g * 2097152;  // [2048][1024]
  const unsigned short* B = SVT + (long)g * 65536;   // [64][1024]
  const int t = threadIdx.x, lane = t & 63, w = t >> 6;   // 2 waves
  const int row0 = blockIdx.x * 128 + w * 64;
  const int ra = lane & 15, kg8 = (lane >> 4) << 3;
  f32x4 acc[4][4] = {};
  short8 a0[4], b0[4], a1[4], b1[4];

#define LDF(as, bs, kk)                                                          \
  do {                                                                           \
    _Pragma("unroll") for (int i = 0; i < 4; ++i)                                \
        as[i] = *(const short8*)(A + (long)(row0 + i * 16 + ra) * 1024 + (kk) + kg8); \
    _Pragma("unroll") for (int j = 0; j < 4; ++j)                                \
        bs[j] = *(const short8*)(B + (long)(j * 16 + ra) * 1024 + (kk) + kg8);   \
  } while (0)
#define MM(as, bs)                                                               \
  do {                                                                           \
    _Pragma("unroll") for (int i = 0; i < 4; ++i)                                \
      _Pragma("unroll") for (int j = 0; j < 4; ++j)                              \
        acc[i][j] = __builtin_amdgcn_mfma_f32_16x16x32_bf16(bs[j], as[i], acc[i][j], 0, 0, 0); \
  } while (0)

  LDF(a0, b0, 0);
  for (int k0 = 0; k0 < 1024; k0 += 64) {
    LDF(a1, b1, k0 + 32);
    MM(a0, b0);
    if (k0 + 64 < 1024) LDF(a0, b0, k0 + 64);
    MM(a1, b1);
  }
#undef LDF
#undef MM

  const int rl = lane & 15, q4 = (lane >> 4) << 2;
#pragma unroll
  for (int i = 0; i < 4; ++i) {
    int rr = row0 + i * 16 + rl;
#pragma unroll
    for (int j = 0; j < 4; ++j) {
      int oc = g * 64 + j * 16 + q4;
      float4 w4 = *(const float4*)(wvb + oc);
      ushort4 r4 = *(const ushort4*)(RS + (long)rr * 1024 + oc);
      float4 o;
      o.x = acc[i][j][0] + w4.x + bf2f(r4.x);
      o.y = acc[i][j][1] + w4.y + bf2f(r4.y);
      o.z = acc[i][j][2] + w4.z + bf2f(r4.z);
      o.w = acc[i][j][3] + w4.w + bf2f(r4.w);
      *(float4*)(out + (long)rr * 1024 + oc) = o;
    }
  }
}

extern "C" void kernel_launch(void* const* d_in, const int* in_sizes, int n_in,
                              void* d_out, int out_size, void* d_ws, size_t ws_size,
                              hipStream_t stream) {
  const float* ref_feat = (const float*)d_in[0];
  const float* sup_feat = (const float*)d_in[1];
  const float* pe       = (const float*)d_in[2];
  const float* fc_w     = (const float*)d_in[3];
  const float* fc_b     = (const float*)d_in[4];
  const float* wg_w     = (const float*)d_in[5];
  const float* wg_b     = (const float*)d_in[6];
  const float* wq_w     = (const float*)d_in[7];
  const float* wq_b     = (const float*)d_in[8];
  const float* wk_w     = (const float*)d_in[9];
  const float* wk_b     = (const float*)d_in[10];
  const float* wv_w     = (const float*)d_in[11];
  const float* wv_b     = (const float*)d_in[12];

  char* ws = (char*)d_ws;
  unsigned short* Xb  = (unsigned short*)(ws);              // [3072][1024]
  unsigned short* FCW = (unsigned short*)(ws + 6291456);
  unsigned short* WQB = (unsigned short*)(ws + 8388608);
  unsigned short* WKB = (unsigned short*)(ws + 10485760);
  unsigned short* WVB = (unsigned short*)(ws + 12582912);
  unsigned short* RS  = (unsigned short*)(ws + 14680064);   // [3072][1024] relu(fc) bf16
  unsigned short* QG  = (unsigned short*)(ws + 20971520);   // [16][2048][64]
  unsigned short* KG  = (unsigned short*)(ws + 25165824);   // [16][1024][64]
  unsigned short* SVT = (unsigned short*)(ws + 27262976);   // [16][64][1024]
  unsigned short* SC  = (unsigned short*)(ws + 29360128);   // [16][2048][1024]

  cvt_all<<<7168, 256, 0, stream>>>(ref_feat, sup_feat, fc_w, wq_w, wk_w, wv_w,
                                    Xb, FCW, WQB, WKB, WVB);
  gemm_fc<<<dim3(24, 8), 256, 0, stream>>>(Xb, FCW, fc_b, RS);
  gemm_qkv<<<dim3(16, 8, 3), 256, 0, stream>>>(RS, WQB, WKB, WVB, wq_b, wk_b, QG, KG, SVT);
  gemm_scores<<<dim3(16, 8, 16), 256, 0, stream>>>(QG, KG, SC);
  pe_softmax<<<2048, 256, 0, stream>>>(pe, wg_w, wg_b, SC);
  gemm_final<<<dim3(16, 1, 16), 128, 0, stream>>>(SC, SVT, RS, wv_b, (float*)d_out);
}